// Round 3
// baseline (208.187 us; speedup 1.0000x reference)
//
#include <hip/hip_runtime.h>
#include <hip/hip_bf16.h>
#include <cstdint>
#include <cstddef>

#define AS1 __attribute__((address_space(1)))
#define AS3 __attribute__((address_space(3)))

typedef __bf16 bf16;
typedef __bf16 bf16x8 __attribute__((ext_vector_type(8)));
typedef float f32x4 __attribute__((ext_vector_type(4)));

static constexpr int M_ROWS = 4096;
static constexpr int N_COLS = 1024;
static constexpr int IN_F   = 1024;
static constexpr int K2     = IN_F * 9;   // 9216: [silu(x) | 8 bases per i]
static constexpr int BK     = 32;         // fallback K-step
static constexpr int KT_CNT = K2 / BK;    // 288 (fallback)

static constexpr int GBK = 64;            // gemm K-step: rows are 128 B = 32 banks
static constexpr int GKT = K2 / GBK;      // 144

// Interface (R8 beacon): inputs f32, dict order, sizes in elements, out f32.

// Closed-form cardinal cubic B-spline over uniform knots t[j] = -2.2 + 0.4*j.
__device__ __forceinline__ void bases8(float x, float w8[8]) {
  float mf = x * 2.5f + 5.5f;           // (x - t0) / h
  int   m  = (int)floorf(mf);
  float u  = mf - (float)m;
  float u2 = u * u, u3 = u2 * u;
  float omu = 1.0f - u;
  const float s = 1.0f / 6.0f;
  float p0 = u3 * s;
  float p1 = (-3.f*u3 + 3.f*u2 + 3.f*u + 1.f) * s;
  float p2 = (3.f*u3 - 6.f*u2 + 4.f) * s;
  float p3 = omu * omu * omu * s;
  bool in = (m >= 0) && (m < 11);
#pragma unroll
  for (int j = 0; j < 8; ++j) {
    float v = 0.0f;
    v = (j == m)     ? p0 : v;
    v = (j == m - 1) ? p1 : v;
    v = (j == m - 2) ? p2 : v;
    v = (j == m - 3) ? p3 : v;
    w8[j] = in ? v : 0.0f;
  }
}

// ---------------------------------------------------------------------------
// Kernel 1: A[b,0:1024]=silu(x); A[b,1024+i*8+j]=basis_j(x[b,i]).
// ---------------------------------------------------------------------------
__global__ void expand_a(const float* __restrict__ x, bf16* __restrict__ A,
                         int r0) {
  int gid = blockIdx.x * blockDim.x + threadIdx.x;
  int b = gid >> 10;
  int i = gid & 1023;
  float xv = x[(size_t)r0 * IN_F + (size_t)gid];

  A[(size_t)b * K2 + i] = (bf16)(xv / (1.0f + __expf(-xv)));

  float w8[8];
  bases8(xv, w8);
  bf16x8 outv;
#pragma unroll
  for (int j = 0; j < 8; ++j) outv[j] = (bf16)w8[j];
  *(bf16x8*)(A + (size_t)b * K2 + IN_F + (size_t)i * 8) = outv;
}

// ---------------------------------------------------------------------------
// Kernel 2: BT[o,0:1024]=bw[o,:]; BT[o,1024+i*8+j]=sw[o,i,j]*sc[o,i].
// ---------------------------------------------------------------------------
__global__ void make_bt(const float* __restrict__ bw, const float* __restrict__ sw,
                        const float* __restrict__ sc, bf16* __restrict__ BT) {
  int gid = blockIdx.x * blockDim.x + threadIdx.x;
  int o = gid >> 10;
  int i = gid & 1023;

  BT[(size_t)o * K2 + i] = (bf16)bw[gid];

  float scale = sc[gid];
  const float4* swp = (const float4*)(sw + (size_t)gid * 8);
  float4 a = swp[0], b4 = swp[1];
  float wv[8] = {a.x, a.y, a.z, a.w, b4.x, b4.y, b4.z, b4.w};
  bf16x8 r;
#pragma unroll
  for (int j = 0; j < 8; ++j) r[j] = (bf16)(wv[j] * scale);
  *(bf16x8*)(BT + (size_t)o * K2 + IN_F + (size_t)i * 8) = r;
}

// ---------------------------------------------------------------------------
// Kernel 3 (R14): out = A @ BT^T, 256x256 block, 8 waves (2M x 4N), wave tile
// 128x64. R13 was LDS-port-bound (~70% of iter = fragment reads + staging
// writes; MfmaUtil 36%). LDS traffic scales with (WM+WN)/(WM*WN): 64x64 ->
// 128x64 cuts reads 2.42->1.81 GB and staging writes 1.21->0.60 GB.
//   - Swizzle chunk^=(row&7) on both sides kept verbatim (measured 0 confl).
//   - 2-buffer ping-pong (128 KB LDS), depth-1 counted vmcnt(8), barrier,
//     compute, barrier — R13's proven schedule, unchanged.
//   - Split-K xS (S=4 preferred): grid S*64, 1 block/CU, full chip.
//   - XCD: mtile = b&15 -> XCD = b%8 = mtile%8; A pinned per XCD (9.4 MB),
//     BT re-reads L3-absorbed (R13 FETCH=110 MB proved this).
//   - T5 setprio around MFMA clusters (8 waves now give role diversity).
// ---------------------------------------------------------------------------
__global__ __launch_bounds__(512, 1) void gemm256(
    const bf16* __restrict__ A, const bf16* __restrict__ BT,
    float* __restrict__ P, int kt_seg) {
  __shared__ bf16 As[2][256 * GBK];   // 2 x 32 KB
  __shared__ bf16 Bs[2][256 * GBK];   // 2 x 32 KB  (128 KB total)

  const int tid  = threadIdx.x;
  const int lane = tid & 63;
  const int w    = tid >> 6;          // 0..7

  const int b     = blockIdx.x;
  const int mtile = b & 15;           // b%8 = mtile%8 -> XCD-pinned A
  const int np    = (b >> 4) & 3;
  const int seg   = b >> 6;
  const int row0  = mtile * 256;
  const int col0  = np * 256;
  const int kt0   = seg * kt_seg;
  float* __restrict__ dst = P + (size_t)seg * M_ROWS * N_COLS;

  // Staging: per global_load_lds a wave writes 8 rows x 128 B linearly;
  // lane l covers (row = l>>3, lds_chunk = l&7). Source chunk = (l&7)^(l>>3)
  // so LDS chunk j of row R holds global chunk j^(R&7).
  const int srow = lane >> 3;
  const int sch  = ((lane & 7) ^ srow) * 8;

  // Fragment reads: row = <base>+r, logical chunk c = kk*4+q, read c^(r&7).
  const int r  = lane & 15;
  const int q  = lane >> 4;
  const int wm = (w >> 2) * 128;      // 2 M-waves
  const int wn = (w & 3) * 64;        // 4 N-waves
  const int kc0 = ((0 + q) ^ (r & 7)) * 8;
  const int kc1 = ((4 + q) ^ (r & 7)) * 8;

  const bf16* aB = A  + (size_t)row0 * K2;
  const bf16* bB = BT + (size_t)col0 * K2;

  f32x4 acc[8][4];
#pragma unroll
  for (int mt = 0; mt < 8; ++mt)
#pragma unroll
    for (int nt = 0; nt < 4; ++nt)
      acc[mt][nt] = f32x4{0.f, 0.f, 0.f, 0.f};

  // Per iter each wave issues 8 global_load_lds (4 A-rowgroups + 4 B-rowgroups
  // of 8 rows): wave w owns rows [w*32, w*32+32) of both 256-row tiles.
  auto stage = [&](int sbuf, int kt) {
#pragma unroll
    for (int t = 0; t < 4; ++t) {
      const int rg = w * 32 + t * 8;
      const bf16* ga = aB + (size_t)(rg + srow) * K2 + kt * GBK + sch;
      __builtin_amdgcn_global_load_lds((const AS1 void*)ga,
                                       (AS3 void*)&As[sbuf][rg * GBK], 16, 0, 0);
      const bf16* gb = bB + (size_t)(rg + srow) * K2 + kt * GBK + sch;
      __builtin_amdgcn_global_load_lds((const AS1 void*)gb,
                                       (AS3 void*)&Bs[sbuf][rg * GBK], 16, 0, 0);
    }
  };

  stage(0, kt0);
  int buf = 0;
  for (int i = 0; i < kt_seg; ++i) {
    if (i + 1 < kt_seg) {
      stage(buf ^ 1, kt0 + i + 1);
      // Outstanding: this iter's 8 (oldest) + next's 8 -> wait the oldest 8.
      asm volatile("s_waitcnt vmcnt(8)" ::: "memory");
    } else {
      asm volatile("s_waitcnt vmcnt(0)" ::: "memory");
    }
    __builtin_amdgcn_s_barrier();          // all waves' tile-i loads landed
    __builtin_amdgcn_sched_barrier(0);

    const bf16* as = As[buf];
    const bf16* bs = Bs[buf];

#pragma unroll
    for (int kk = 0; kk < 2; ++kk) {
      const int kc = kk ? kc1 : kc0;
      bf16x8 af[8], bfr[4];
#pragma unroll
      for (int mt = 0; mt < 8; ++mt)
        af[mt] = *(const bf16x8*)&as[(wm + mt * 16 + r) * GBK + kc];
#pragma unroll
      for (int nt = 0; nt < 4; ++nt)
        bfr[nt] = *(const bf16x8*)&bs[(wn + nt * 16 + r) * GBK + kc];
      __builtin_amdgcn_s_setprio(1);
#pragma unroll
      for (int mt = 0; mt < 8; ++mt)
#pragma unroll
        for (int nt = 0; nt < 4; ++nt)
          acc[mt][nt] = __builtin_amdgcn_mfma_f32_16x16x32_bf16(
              af[mt], bfr[nt], acc[mt][nt], 0, 0, 0);
      __builtin_amdgcn_s_setprio(0);
    }
    __builtin_amdgcn_s_barrier();          // WAR fence: reads done before
    buf ^= 1;                              // this buffer is re-staged
  }

  // f32 epilogue: C/D layout col = lane&15, row = (lane>>4)*4 + reg
#pragma unroll
  for (int mt = 0; mt < 8; ++mt)
#pragma unroll
    for (int nt = 0; nt < 4; ++nt)
#pragma unroll
      for (int k = 0; k < 4; ++k) {
        int row = row0 + wm + mt * 16 + q * 4 + k;
        int col = col0 + wn + nt * 16 + r;
        dst[(size_t)row * N_COLS + col] = acc[mt][nt][k];
      }
}

// ---------------------------------------------------------------------------
// Kernel 3b (R13's 128x128 gemm, kept for fallback slab path).
// ---------------------------------------------------------------------------
__global__ __launch_bounds__(256, 2) void gemm_fused(
    const bf16* __restrict__ A, const bf16* __restrict__ BT,
    float* __restrict__ d0, float* __restrict__ d1,
    int r0, int mt_cnt, int kt_seg) {
  __shared__ bf16 As[2][128 * GBK];
  __shared__ bf16 Bs[2][128 * GBK];

  const int tid  = threadIdx.x;
  const int lane = tid & 63;
  const int w    = tid >> 6;

  const int bps = mt_cnt * 8;
  int b   = blockIdx.x;
  const int seg = b / bps;
  b -= seg * bps;
  const int row0 = (b % mt_cnt) * 128;
  const int col0 = (b / mt_cnt) * 128;
  float* __restrict__ dst = seg ? d1 : d0;
  const int kt0 = seg * kt_seg;

  const int srow = lane >> 3;
  const int sch  = ((lane & 7) ^ srow) * 8;
  const int r  = lane & 15;
  const int q  = lane >> 4;
  const int wm = (w >> 1) * 64;
  const int wn = (w & 1) * 64;
  const int kc0 = ((0 + q) ^ (r & 7)) * 8;
  const int kc1 = ((4 + q) ^ (r & 7)) * 8;

  const bf16* aB = A  + (size_t)row0 * K2;
  const bf16* bB = BT + (size_t)col0 * K2;

  f32x4 acc[4][4];
#pragma unroll
  for (int mt = 0; mt < 4; ++mt)
#pragma unroll
    for (int nt = 0; nt < 4; ++nt)
      acc[mt][nt] = f32x4{0.f, 0.f, 0.f, 0.f};

  auto stage = [&](int sbuf, int kt) {
#pragma unroll
    for (int t = 0; t < 4; ++t) {
      const int rg = w * 32 + t * 8;
      const bf16* ga = aB + (size_t)(rg + srow) * K2 + kt * GBK + sch;
      __builtin_amdgcn_global_load_lds((const AS1 void*)ga,
                                       (AS3 void*)&As[sbuf][rg * GBK], 16, 0, 0);
      const bf16* gb = bB + (size_t)(rg + srow) * K2 + kt * GBK + sch;
      __builtin_amdgcn_global_load_lds((const AS1 void*)gb,
                                       (AS3 void*)&Bs[sbuf][rg * GBK], 16, 0, 0);
    }
  };

  stage(0, kt0);
  int buf = 0;
  for (int i = 0; i < kt_seg; ++i) {
    if (i + 1 < kt_seg) {
      stage(buf ^ 1, kt0 + i + 1);
      asm volatile("s_waitcnt vmcnt(8)" ::: "memory");
    } else {
      asm volatile("s_waitcnt vmcnt(0)" ::: "memory");
    }
    __builtin_amdgcn_s_barrier();
    __builtin_amdgcn_sched_barrier(0);

    const bf16* as = As[buf];
    const bf16* bs = Bs[buf];

#pragma unroll
    for (int kk = 0; kk < 2; ++kk) {
      const int kc = kk ? kc1 : kc0;
      bf16x8 af[4], bfr[4];
#pragma unroll
      for (int mt = 0; mt < 4; ++mt)
        af[mt] = *(const bf16x8*)&as[(wm + mt * 16 + r) * GBK + kc];
#pragma unroll
      for (int nt = 0; nt < 4; ++nt)
        bfr[nt] = *(const bf16x8*)&bs[(wn + nt * 16 + r) * GBK + kc];
#pragma unroll
      for (int mt = 0; mt < 4; ++mt)
#pragma unroll
        for (int nt = 0; nt < 4; ++nt)
          acc[mt][nt] = __builtin_amdgcn_mfma_f32_16x16x32_bf16(
              af[mt], bfr[nt], acc[mt][nt], 0, 0, 0);
    }
    __builtin_amdgcn_s_barrier();
    buf ^= 1;
  }

#pragma unroll
  for (int mt = 0; mt < 4; ++mt)
#pragma unroll
    for (int nt = 0; nt < 4; ++nt)
#pragma unroll
      for (int k = 0; k < 4; ++k) {
        int row = r0 + row0 + wm + mt * 16 + q * 4 + k;
        int col = col0 + wn + nt * 16 + r;
        dst[(size_t)row * N_COLS + col] = acc[mt][nt][k];
      }
}

// ---------------------------------------------------------------------------
// Kernel 4: out = sum of S partial planes, f32x4 vectorized.
// ---------------------------------------------------------------------------
__global__ void reduce_addN(const float* __restrict__ P,
                            float* __restrict__ out, int segs) {
  size_t i = (size_t)blockIdx.x * blockDim.x + threadIdx.x;
  const f32x4* p = (const f32x4*)P;
  const size_t plane = (size_t)M_ROWS * N_COLS / 4;
  f32x4 a = p[i];
  for (int s = 1; s < segs; ++s) a += p[(size_t)s * plane + i];
  ((f32x4*)out)[i] = a;
}

// ---------------------------------------------------------------------------
// Fallback (ws too small — not expected; SL=4096 confirmed in R9/R10).
// ---------------------------------------------------------------------------
__global__ __launch_bounds__(256) void kan_fused_fallback(
    const float* __restrict__ x, const float* __restrict__ bw,
    const float* __restrict__ sw, const float* __restrict__ sc,
    float* __restrict__ out) {
  __shared__ bf16 As[64 * BK];
  __shared__ bf16 Bs[128 * BK];
  const int tid  = threadIdx.x;
  const int lane = tid & 63;
  const int w    = tid >> 6;
  const int col0 = blockIdx.x * 128;
  const int row0 = blockIdx.y * 64;
  const int srow = tid >> 2, sq = tid & 3;
  const int r = lane & 15, q = lane >> 4, wn = w * 32;

  f32x4 acc[4][2];
#pragma unroll
  for (int mt = 0; mt < 4; ++mt)
#pragma unroll
    for (int nt = 0; nt < 2; ++nt) acc[mt][nt] = f32x4{0,0,0,0};

  for (int kt = 0; kt < KT_CNT; ++kt) {
    if (kt < 32) {
      const int cc = sq * 8;
      const float4* xp = (const float4*)(x + (size_t)(row0+srow)*IN_F + kt*BK + cc);
      float4 a = xp[0], b4 = xp[1];
      float xv[8] = {a.x,a.y,a.z,a.w,b4.x,b4.y,b4.z,b4.w};
      bf16x8 av;
#pragma unroll
      for (int j = 0; j < 8; ++j) av[j] = (bf16)(xv[j] / (1.0f + __expf(-xv[j])));
      *(bf16x8*)&As[srow * BK + cc] = av;
#pragma unroll
      for (int h = 0; h < 2; ++h) {
        const float4* bp = (const float4*)(bw + (size_t)(col0+h*64+srow)*IN_F + kt*BK + cc);
        float4 c0 = bp[0], c1 = bp[1];
        float bv[8] = {c0.x,c0.y,c0.z,c0.w,c1.x,c1.y,c1.z,c1.w};
        bf16x8 bb;
#pragma unroll
        for (int j = 0; j < 8; ++j) bb[j] = (bf16)bv[j];
        *(bf16x8*)&Bs[(h*64+srow)*BK + cc] = bb;
      }
    } else {
      const int i = (kt - 32) * 4 + sq;
      float xv = x[(size_t)(row0+srow)*IN_F + i];
      float w8[8]; bases8(xv, w8);
      bf16x8 av;
#pragma unroll
      for (int j = 0; j < 8; ++j) av[j] = (bf16)w8[j];
      *(bf16x8*)&As[srow * BK + sq * 8] = av;
#pragma unroll
      for (int h = 0; h < 2; ++h) {
        const int o = col0 + h*64 + srow;
        float s1 = sc[(size_t)o*IN_F + i];
        const float4* sp = (const float4*)(sw + ((size_t)o*IN_F + i)*8);
        float4 c0 = sp[0], c1 = sp[1];
        float wv[8] = {c0.x,c0.y,c0.z,c0.w,c1.x,c1.y,c1.z,c1.w};
        bf16x8 bb;
#pragma unroll
        for (int j = 0; j < 8; ++j) bb[j] = (bf16)(wv[j]*s1);
        *(bf16x8*)&Bs[(h*64+srow)*BK + sq*8] = bb;
      }
    }
    __syncthreads();
    bf16x8 af[4], bfr[2];
#pragma unroll
    for (int mt = 0; mt < 4; ++mt)
      af[mt] = *(const bf16x8*)&As[(mt*16+r)*BK + q*8];
#pragma unroll
    for (int nt = 0; nt < 2; ++nt)
      bfr[nt] = *(const bf16x8*)&Bs[(wn+nt*16+r)*BK + q*8];
#pragma unroll
    for (int mt = 0; mt < 4; ++mt)
#pragma unroll
      for (int nt = 0; nt < 2; ++nt)
        acc[mt][nt] = __builtin_amdgcn_mfma_f32_16x16x32_bf16(af[mt], bfr[nt], acc[mt][nt], 0,0,0);
    __syncthreads();
  }
#pragma unroll
  for (int mt = 0; mt < 4; ++mt)
#pragma unroll
    for (int nt = 0; nt < 2; ++nt)
#pragma unroll
      for (int k = 0; k < 4; ++k)
        out[(size_t)(row0+mt*16+q*4+k)*N_COLS + col0+wn+nt*16+r] = acc[mt][nt][k];
}

extern "C" void kernel_launch(void* const* d_in, const int* in_sizes, int n_in,
                              void* d_out, int out_size, void* d_ws, size_t ws_size,
                              hipStream_t stream) {
  const float* x    = (const float*)d_in[0];
  const float* bw   = (const float*)d_in[1];
  const float* sw   = (const float*)d_in[2];
  const float* sc   = (const float*)d_in[3];
  float* out = (float*)d_out;

  const size_t BT_BYTES  = (size_t)N_COLS * K2 * sizeof(bf16);   // 18.9 MB
  const size_t ROW_BYTES = (size_t)K2 * sizeof(bf16);            // 18 KB
  const size_t A_BYTES   = (size_t)M_ROWS * ROW_BYTES;           // 75.5 MB
  const size_t OUT_BYTES = (size_t)M_ROWS * N_COLS * sizeof(float); // 16.8 MB

  // Split-K ladder: S=4 (full chip) -> 3 -> 2, whatever fits in ws.
  int S = 0;
  for (int c = 4; c >= 2; --c)
    if (GKT % c == 0 && BT_BYTES + A_BYTES + (size_t)c * OUT_BYTES <= ws_size) {
      S = c; break;
    }

  if (S >= 2) {
    bf16*  BT    = (bf16*)d_ws;
    bf16*  Aslab = BT + (size_t)N_COLS * K2;
    float* P     = (float*)((char*)d_ws + BT_BYTES + A_BYTES);
    make_bt<<<(N_COLS * IN_F) / 256, 256, 0, stream>>>(bw, sw, sc, BT);
    expand_a<<<(M_ROWS * IN_F) / 256, 256, 0, stream>>>(x, Aslab, 0);
    gemm256<<<S * 64, 512, 0, stream>>>(Aslab, BT, P, GKT / S);
    reduce_addN<<<(M_ROWS * N_COLS) / (4 * 256), 256, 0, stream>>>(P, out, S);
  } else {
    int SL = 0;
    for (int cand = 4096; cand >= 128; cand >>= 1)
      if (BT_BYTES + (size_t)cand * ROW_BYTES <= ws_size) { SL = cand; break; }
    if (SL) {
      bf16* BT    = (bf16*)d_ws;
      bf16* Aslab = BT + (size_t)N_COLS * K2;
      make_bt<<<(N_COLS * IN_F) / 256, 256, 0, stream>>>(bw, sw, sc, BT);
      for (int r0 = 0; r0 < M_ROWS; r0 += SL) {
        expand_a<<<(SL * IN_F) / 256, 256, 0, stream>>>(x, Aslab, r0);
        gemm_fused<<<(SL / 128) * (N_COLS / 128), 256, 0, stream>>>(
            Aslab, BT, out, out, r0, SL / 128, GKT);
      }
    } else {
      kan_fused_fallback<<<dim3(N_COLS / 128, M_ROWS / 64), 256, 0, stream>>>(
          x, bw, sw, sc, out);
    }
  }
  (void)in_sizes; (void)n_in; (void)out_size;
}

// Round 4
// 201.219 us; speedup vs baseline: 1.0346x; 1.0346x over previous
//
#include <hip/hip_runtime.h>
#include <hip/hip_bf16.h>
#include <cstdint>
#include <cstddef>

#define AS1 __attribute__((address_space(1)))
#define AS3 __attribute__((address_space(3)))

typedef __bf16 bf16;
typedef __bf16 bf16x8 __attribute__((ext_vector_type(8)));
typedef float f32x4 __attribute__((ext_vector_type(4)));

static constexpr int M_ROWS = 4096;
static constexpr int N_COLS = 1024;
static constexpr int IN_F   = 1024;
static constexpr int K2     = IN_F * 9;   // 9216: [silu(x) | 8 bases per i]
static constexpr int BK     = 32;         // fallback K-step
static constexpr int KT_CNT = K2 / BK;    // 288 (fallback)

static constexpr int GBK = 64;            // gemm K-step: rows are 128 B = 32 banks
static constexpr int GKT = K2 / GBK;      // 144

// Interface (R8 beacon): inputs f32, dict order, sizes in elements, out f32.

// Closed-form cardinal cubic B-spline over uniform knots t[j] = -2.2 + 0.4*j.
__device__ __forceinline__ void bases8(float x, float w8[8]) {
  float mf = x * 2.5f + 5.5f;           // (x - t0) / h
  int   m  = (int)floorf(mf);
  float u  = mf - (float)m;
  float u2 = u * u, u3 = u2 * u;
  float omu = 1.0f - u;
  const float s = 1.0f / 6.0f;
  float p0 = u3 * s;
  float p1 = (-3.f*u3 + 3.f*u2 + 3.f*u + 1.f) * s;
  float p2 = (3.f*u3 - 6.f*u2 + 4.f) * s;
  float p3 = omu * omu * omu * s;
  bool in = (m >= 0) && (m < 11);
#pragma unroll
  for (int j = 0; j < 8; ++j) {
    float v = 0.0f;
    v = (j == m)     ? p0 : v;
    v = (j == m - 1) ? p1 : v;
    v = (j == m - 2) ? p2 : v;
    v = (j == m - 3) ? p3 : v;
    w8[j] = in ? v : 0.0f;
  }
}

__device__ __forceinline__ void expand_body(const float* __restrict__ x,
                                            bf16* __restrict__ A, int gid, int r0) {
  int b = gid >> 10;
  int i = gid & 1023;
  float xv = x[(size_t)r0 * IN_F + (size_t)gid];
  A[(size_t)b * K2 + i] = (bf16)(xv / (1.0f + __expf(-xv)));
  float w8[8];
  bases8(xv, w8);
  bf16x8 outv;
#pragma unroll
  for (int j = 0; j < 8; ++j) outv[j] = (bf16)w8[j];
  *(bf16x8*)(A + (size_t)b * K2 + IN_F + (size_t)i * 8) = outv;
}

__device__ __forceinline__ void makebt_body(const float* __restrict__ bw,
                                            const float* __restrict__ sw,
                                            const float* __restrict__ sc,
                                            bf16* __restrict__ BT, int gid) {
  int o = gid >> 10;
  int i = gid & 1023;
  BT[(size_t)o * K2 + i] = (bf16)bw[gid];
  float scale = sc[gid];
  const float4* swp = (const float4*)(sw + (size_t)gid * 8);
  float4 a = swp[0], b4 = swp[1];
  float wv[8] = {a.x, a.y, a.z, a.w, b4.x, b4.y, b4.z, b4.w};
  bf16x8 r;
#pragma unroll
  for (int j = 0; j < 8; ++j) r[j] = (bf16)(wv[j] * scale);
  *(bf16x8*)(BT + (size_t)o * K2 + IN_F + (size_t)i * 8) = r;
}

// ---------------------------------------------------------------------------
// Kernel 1 (fused prep): blocks [0,16384) expand A; [16384,20480) build BT.
// ---------------------------------------------------------------------------
__global__ void prep(const float* __restrict__ x, const float* __restrict__ bw,
                     const float* __restrict__ sw, const float* __restrict__ sc,
                     bf16* __restrict__ A, bf16* __restrict__ BT) {
  int bid = blockIdx.x;
  if (bid < (M_ROWS * IN_F) / 256) {
    expand_body(x, A, bid * 256 + threadIdx.x, 0);
  } else {
    makebt_body(bw, sw, sc, BT, (bid - (M_ROWS * IN_F) / 256) * 256 + threadIdx.x);
  }
}

// Standalone versions for the slab fallback path.
__global__ void expand_a(const float* __restrict__ x, bf16* __restrict__ A, int r0) {
  expand_body(x, A, blockIdx.x * blockDim.x + threadIdx.x, r0);
}
__global__ void make_bt(const float* __restrict__ bw, const float* __restrict__ sw,
                        const float* __restrict__ sc, bf16* __restrict__ BT) {
  makebt_body(bw, sw, sc, BT, blockIdx.x * blockDim.x + threadIdx.x);
}

// ---------------------------------------------------------------------------
// Kernel 3 (R15): 8-phase-schedule 256x256 GEMM (T3+T4 port per the regime
// table: 2-phase 256-tile measured 878 TF = the documented 2-barrier ceiling;
// R13->R14 tile change was a no-op, proving schedule-bound not LDS-bound).
//   Geometry (R14, proven): 8 waves 2Mx4N, wave 128x64, GBK=64, swizzle
//   chunk^=(row&7) both sides (0 conflicts), split-K x4, XCD map b&15.
//   Schedule: per K-tile 4 phases; phase = {ds_reads for this quadrant |
//   stage 1 half-tile | barrier | lgkmcnt(0)+sched_barrier | setprio(1)
//   16 MFMA setprio(0) | barrier}. Quadrants Q0..Q3 with af/bfr reg reuse
//   (reads 12/4/8/0). Staging lookahead: H0(A-lo)@P3(t-1), H1(A-hi)@P0,
//   H2(B-lo)@P1, H3(B-hi)@P2; ONE vmcnt(2) per tile at P3 (10 in flight,
//   wait 8 oldest = next tile landed; never 0 except tail).
//   WAR-safety: A of buf last read at P2 (fenced by P2's lgkmcnt(0) asm +
//   P2-end barrier) before P3 stages into it; B last read at P1, staged at
//   P1/P2 of the NEXT tile into the other buffer.
// ---------------------------------------------------------------------------
__global__ __launch_bounds__(512, 2) void gemm256_8p(
    const bf16* __restrict__ A, const bf16* __restrict__ BT,
    float* __restrict__ P, int kt_seg) {
  __shared__ bf16 As[2][256 * GBK];   // 2 x 32 KB
  __shared__ bf16 Bs[2][256 * GBK];   // 2 x 32 KB  (128 KB)

  const int tid  = threadIdx.x;
  const int lane = tid & 63;
  const int w    = tid >> 6;          // 0..7

  const int b     = blockIdx.x;
  const int mtile = b & 15;           // XCD = b&7 = mtile&7 -> A pinned
  const int np    = (b >> 4) & 3;
  const int seg   = b >> 6;
  const int row0  = mtile * 256;
  const int col0  = np * 256;
  const int kt0   = seg * kt_seg;
  float* __restrict__ dst = P + (size_t)seg * M_ROWS * N_COLS;

  // Staging swizzle (R12-R14 proven): lane l covers (row l>>3, lds chunk l&7);
  // source chunk (l&7)^(l>>3) -> LDS chunk j of row R holds global chunk j^(R&7).
  const int srow = lane >> 3;
  const int sch  = ((lane & 7) ^ srow) * 8;

  const int r  = lane & 15;
  const int q  = lane >> 4;
  const int wm = (w >> 2) * 128;
  const int wn = (w & 3) * 64;
  const int kc0 = ((0 + q) ^ (r & 7)) * 8;   // logical chunk kk*4+q, ^(row&7)
  const int kc1 = ((4 + q) ^ (r & 7)) * 8;

  const bf16* aB = A  + (size_t)row0 * K2;
  const bf16* bB = BT + (size_t)col0 * K2;

  f32x4 acc[8][4];
#pragma unroll
  for (int mt = 0; mt < 8; ++mt)
#pragma unroll
    for (int nt = 0; nt < 4; ++nt)
      acc[mt][nt] = f32x4{0.f, 0.f, 0.f, 0.f};

  // One half-tile = 128 rows; per wave 2 loads (8 rows x 128 B each, linear).
  auto stageA = [&](int sbuf, int h, int kt) {
#pragma unroll
    for (int t8 = 0; t8 < 2; ++t8) {
      const int rg = h * 128 + w * 16 + t8 * 8;
      const bf16* ga = aB + (size_t)(rg + srow) * K2 + kt * GBK + sch;
      __builtin_amdgcn_global_load_lds((const AS1 void*)ga,
                                       (AS3 void*)&As[sbuf][rg * GBK], 16, 0, 0);
    }
  };
  auto stageB = [&](int sbuf, int h, int kt) {
#pragma unroll
    for (int t8 = 0; t8 < 2; ++t8) {
      const int rg = h * 128 + w * 16 + t8 * 8;
      const bf16* gb = bB + (size_t)(rg + srow) * K2 + kt * GBK + sch;
      __builtin_amdgcn_global_load_lds((const AS1 void*)gb,
                                       (AS3 void*)&Bs[sbuf][rg * GBK], 16, 0, 0);
    }
  };

  // Prologue: tile0 fully + tile1's A-lo (= steady-state P3(t-1) slot).
  stageA(0, 0, kt0); stageA(0, 1, kt0);
  stageB(0, 0, kt0); stageB(0, 1, kt0);
  if (kt_seg > 1) stageA(1, 0, kt0 + 1);
  if (kt_seg > 1) asm volatile("s_waitcnt vmcnt(2)" ::: "memory");
  else            asm volatile("s_waitcnt vmcnt(0)" ::: "memory");
  __builtin_amdgcn_s_barrier();

  bf16x8 af[4][2], bfr[4][2];

  for (int t = 0; t < kt_seg; ++t) {
    const int buf = t & 1, nbuf = buf ^ 1;
    const bf16* as = As[buf];
    const bf16* bs = Bs[buf];
    const bool sN = (t + 1 < kt_seg);   // stage tile t+1 exists

    // ---- P0: reads af(mt0-3)+bfr(nt0-1) [12]; stage(t+1, A-hi); Q0 ----
#pragma unroll
    for (int j = 0; j < 4; ++j) {
      const bf16* ar = &as[(wm + j * 16 + r) * GBK];
      af[j][0] = *(const bf16x8*)&ar[kc0];
      af[j][1] = *(const bf16x8*)&ar[kc1];
    }
#pragma unroll
    for (int j = 0; j < 2; ++j) {
      const bf16* br = &bs[(wn + j * 16 + r) * GBK];
      bfr[j][0] = *(const bf16x8*)&br[kc0];
      bfr[j][1] = *(const bf16x8*)&br[kc1];
    }
    if (sN) stageA(nbuf, 1, kt0 + t + 1);
    asm volatile("s_waitcnt lgkmcnt(8)" ::: "memory");
    __builtin_amdgcn_s_barrier();
    asm volatile("s_waitcnt lgkmcnt(0)" ::: "memory");
    __builtin_amdgcn_sched_barrier(0);
    __builtin_amdgcn_s_setprio(1);
#pragma unroll
    for (int j = 0; j < 4; ++j)
#pragma unroll
      for (int n = 0; n < 2; ++n) {
        acc[j][n] = __builtin_amdgcn_mfma_f32_16x16x32_bf16(af[j][0], bfr[n][0], acc[j][n], 0, 0, 0);
        acc[j][n] = __builtin_amdgcn_mfma_f32_16x16x32_bf16(af[j][1], bfr[n][1], acc[j][n], 0, 0, 0);
      }
    __builtin_amdgcn_s_setprio(0);
    __builtin_amdgcn_s_barrier();

    // ---- P1: reads bfr(nt2-3) [4]; stage(t+1, B-lo); Q1 ----
#pragma unroll
    for (int j = 0; j < 2; ++j) {
      const bf16* br = &bs[(wn + (2 + j) * 16 + r) * GBK];
      bfr[2 + j][0] = *(const bf16x8*)&br[kc0];
      bfr[2 + j][1] = *(const bf16x8*)&br[kc1];
    }
    if (sN) stageB(nbuf, 0, kt0 + t + 1);
    __builtin_amdgcn_s_barrier();
    asm volatile("s_waitcnt lgkmcnt(0)" ::: "memory");
    __builtin_amdgcn_sched_barrier(0);
    __builtin_amdgcn_s_setprio(1);
#pragma unroll
    for (int j = 0; j < 4; ++j)
#pragma unroll
      for (int n = 0; n < 2; ++n) {
        acc[j][2 + n] = __builtin_amdgcn_mfma_f32_16x16x32_bf16(af[j][0], bfr[2 + n][0], acc[j][2 + n], 0, 0, 0);
        acc[j][2 + n] = __builtin_amdgcn_mfma_f32_16x16x32_bf16(af[j][1], bfr[2 + n][1], acc[j][2 + n], 0, 0, 0);
      }
    __builtin_amdgcn_s_setprio(0);
    __builtin_amdgcn_s_barrier();

    // ---- P2: reads af(mt4-7) [8]; stage(t+1, B-hi); Q2 ----
#pragma unroll
    for (int j = 0; j < 4; ++j) {
      const bf16* ar = &as[(wm + (4 + j) * 16 + r) * GBK];
      af[j][0] = *(const bf16x8*)&ar[kc0];
      af[j][1] = *(const bf16x8*)&ar[kc1];
    }
    if (sN) stageB(nbuf, 1, kt0 + t + 1);
    __builtin_amdgcn_s_barrier();
    asm volatile("s_waitcnt lgkmcnt(0)" ::: "memory");
    __builtin_amdgcn_sched_barrier(0);
    __builtin_amdgcn_s_setprio(1);
#pragma unroll
    for (int j = 0; j < 4; ++j)
#pragma unroll
      for (int n = 0; n < 2; ++n) {
        acc[4 + j][n] = __builtin_amdgcn_mfma_f32_16x16x32_bf16(af[j][0], bfr[n][0], acc[4 + j][n], 0, 0, 0);
        acc[4 + j][n] = __builtin_amdgcn_mfma_f32_16x16x32_bf16(af[j][1], bfr[n][1], acc[4 + j][n], 0, 0, 0);
      }
    __builtin_amdgcn_s_setprio(0);
    __builtin_amdgcn_s_barrier();

    // ---- P3: no reads; stage(t+2, A-lo) into freed buf; vmcnt; Q3 ----
    if (t + 2 < kt_seg) stageA(buf, 0, kt0 + t + 2);
    if (sN) {
      if (t + 2 < kt_seg) asm volatile("s_waitcnt vmcnt(2)" ::: "memory");
      else                asm volatile("s_waitcnt vmcnt(0)" ::: "memory");
    }
    __builtin_amdgcn_s_barrier();
    __builtin_amdgcn_s_setprio(1);
#pragma unroll
    for (int j = 0; j < 4; ++j)
#pragma unroll
      for (int n = 0; n < 2; ++n) {
        acc[4 + j][2 + n] = __builtin_amdgcn_mfma_f32_16x16x32_bf16(af[j][0], bfr[2 + n][0], acc[4 + j][2 + n], 0, 0, 0);
        acc[4 + j][2 + n] = __builtin_amdgcn_mfma_f32_16x16x32_bf16(af[j][1], bfr[2 + n][1], acc[4 + j][2 + n], 0, 0, 0);
      }
    __builtin_amdgcn_s_setprio(0);
    __builtin_amdgcn_s_barrier();
  }

  // f32 epilogue: C/D layout col = lane&15, row = (lane>>4)*4 + reg
#pragma unroll
  for (int mt = 0; mt < 8; ++mt)
#pragma unroll
    for (int nt = 0; nt < 4; ++nt)
#pragma unroll
      for (int k = 0; k < 4; ++k) {
        int row = row0 + wm + mt * 16 + q * 4 + k;
        int col = col0 + wn + nt * 16 + r;
        dst[(size_t)row * N_COLS + col] = acc[mt][nt][k];
      }
}

// ---------------------------------------------------------------------------
// Kernel 3b (R13's 128x128 gemm, kept for fallback slab path).
// ---------------------------------------------------------------------------
__global__ __launch_bounds__(256, 2) void gemm_fused(
    const bf16* __restrict__ A, const bf16* __restrict__ BT,
    float* __restrict__ d0, float* __restrict__ d1,
    int r0, int mt_cnt, int kt_seg) {
  __shared__ bf16 As[2][128 * GBK];
  __shared__ bf16 Bs[2][128 * GBK];

  const int tid  = threadIdx.x;
  const int lane = tid & 63;
  const int w    = tid >> 6;

  const int bps = mt_cnt * 8;
  int b   = blockIdx.x;
  const int seg = b / bps;
  b -= seg * bps;
  const int row0 = (b % mt_cnt) * 128;
  const int col0 = (b / mt_cnt) * 128;
  float* __restrict__ dst = seg ? d1 : d0;
  const int kt0 = seg * kt_seg;

  const int srow = lane >> 3;
  const int sch  = ((lane & 7) ^ srow) * 8;
  const int r  = lane & 15;
  const int q  = lane >> 4;
  const int wm = (w >> 1) * 64;
  const int wn = (w & 1) * 64;
  const int kc0 = ((0 + q) ^ (r & 7)) * 8;
  const int kc1 = ((4 + q) ^ (r & 7)) * 8;

  const bf16* aB = A  + (size_t)row0 * K2;
  const bf16* bB = BT + (size_t)col0 * K2;

  f32x4 acc[4][4];
#pragma unroll
  for (int mt = 0; mt < 4; ++mt)
#pragma unroll
    for (int nt = 0; nt < 4; ++nt)
      acc[mt][nt] = f32x4{0.f, 0.f, 0.f, 0.f};

  auto stage = [&](int sbuf, int kt) {
#pragma unroll
    for (int t = 0; t < 4; ++t) {
      const int rg = w * 32 + t * 8;
      const bf16* ga = aB + (size_t)(rg + srow) * K2 + kt * GBK + sch;
      __builtin_amdgcn_global_load_lds((const AS1 void*)ga,
                                       (AS3 void*)&As[sbuf][rg * GBK], 16, 0, 0);
      const bf16* gb = bB + (size_t)(rg + srow) * K2 + kt * GBK + sch;
      __builtin_amdgcn_global_load_lds((const AS1 void*)gb,
                                       (AS3 void*)&Bs[sbuf][rg * GBK], 16, 0, 0);
    }
  };

  stage(0, kt0);
  int buf = 0;
  for (int i = 0; i < kt_seg; ++i) {
    if (i + 1 < kt_seg) {
      stage(buf ^ 1, kt0 + i + 1);
      asm volatile("s_waitcnt vmcnt(8)" ::: "memory");
    } else {
      asm volatile("s_waitcnt vmcnt(0)" ::: "memory");
    }
    __builtin_amdgcn_s_barrier();
    __builtin_amdgcn_sched_barrier(0);

    const bf16* as = As[buf];
    const bf16* bs = Bs[buf];

#pragma unroll
    for (int kk = 0; kk < 2; ++kk) {
      const int kc = kk ? kc1 : kc0;
      bf16x8 af[4], bfr[4];
#pragma unroll
      for (int mt = 0; mt < 4; ++mt)
        af[mt] = *(const bf16x8*)&as[(wm + mt * 16 + r) * GBK + kc];
#pragma unroll
      for (int nt = 0; nt < 4; ++nt)
        bfr[nt] = *(const bf16x8*)&bs[(wn + nt * 16 + r) * GBK + kc];
#pragma unroll
      for (int mt = 0; mt < 4; ++mt)
#pragma unroll
        for (int nt = 0; nt < 4; ++nt)
          acc[mt][nt] = __builtin_amdgcn_mfma_f32_16x16x32_bf16(
              af[mt], bfr[nt], acc[mt][nt], 0, 0, 0);
    }
    __builtin_amdgcn_s_barrier();
    buf ^= 1;
  }

#pragma unroll
  for (int mt = 0; mt < 4; ++mt)
#pragma unroll
    for (int nt = 0; nt < 4; ++nt)
#pragma unroll
      for (int k = 0; k < 4; ++k) {
        int row = r0 + row0 + wm + mt * 16 + q * 4 + k;
        int col = col0 + wn + nt * 16 + r;
        dst[(size_t)row * N_COLS + col] = acc[mt][nt][k];
      }
}

// ---------------------------------------------------------------------------
// Kernel 4: out = sum of S partial planes, f32x4 vectorized.
// ---------------------------------------------------------------------------
__global__ void reduce_addN(const float* __restrict__ P,
                            float* __restrict__ out, int segs) {
  size_t i = (size_t)blockIdx.x * blockDim.x + threadIdx.x;
  const f32x4* p = (const f32x4*)P;
  const size_t plane = (size_t)M_ROWS * N_COLS / 4;
  f32x4 a = p[i];
  for (int s = 1; s < segs; ++s) a += p[(size_t)s * plane + i];
  ((f32x4*)out)[i] = a;
}

// ---------------------------------------------------------------------------
// Fallback (ws too small — not expected; SL=4096 confirmed in R9/R10).
// ---------------------------------------------------------------------------
__global__ __launch_bounds__(256) void kan_fused_fallback(
    const float* __restrict__ x, const float* __restrict__ bw,
    const float* __restrict__ sw, const float* __restrict__ sc,
    float* __restrict__ out) {
  __shared__ bf16 As[64 * BK];
  __shared__ bf16 Bs[128 * BK];
  const int tid  = threadIdx.x;
  const int lane = tid & 63;
  const int w    = tid >> 6;
  const int col0 = blockIdx.x * 128;
  const int row0 = blockIdx.y * 64;
  const int srow = tid >> 2, sq = tid & 3;
  const int r = lane & 15, q = lane >> 4, wn = w * 32;

  f32x4 acc[4][2];
#pragma unroll
  for (int mt = 0; mt < 4; ++mt)
#pragma unroll
    for (int nt = 0; nt < 2; ++nt) acc[mt][nt] = f32x4{0,0,0,0};

  for (int kt = 0; kt < KT_CNT; ++kt) {
    if (kt < 32) {
      const int cc = sq * 8;
      const float4* xp = (const float4*)(x + (size_t)(row0+srow)*IN_F + kt*BK + cc);
      float4 a = xp[0], b4 = xp[1];
      float xv[8] = {a.x,a.y,a.z,a.w,b4.x,b4.y,b4.z,b4.w};
      bf16x8 av;
#pragma unroll
      for (int j = 0; j < 8; ++j) av[j] = (bf16)(xv[j] / (1.0f + __expf(-xv[j])));
      *(bf16x8*)&As[srow * BK + cc] = av;
#pragma unroll
      for (int h = 0; h < 2; ++h) {
        const float4* bp = (const float4*)(bw + (size_t)(col0+h*64+srow)*IN_F + kt*BK + cc);
        float4 c0 = bp[0], c1 = bp[1];
        float bv[8] = {c0.x,c0.y,c0.z,c0.w,c1.x,c1.y,c1.z,c1.w};
        bf16x8 bb;
#pragma unroll
        for (int j = 0; j < 8; ++j) bb[j] = (bf16)bv[j];
        *(bf16x8*)&Bs[(h*64+srow)*BK + cc] = bb;
      }
    } else {
      const int i = (kt - 32) * 4 + sq;
      float xv = x[(size_t)(row0+srow)*IN_F + i];
      float w8[8]; bases8(xv, w8);
      bf16x8 av;
#pragma unroll
      for (int j = 0; j < 8; ++j) av[j] = (bf16)w8[j];
      *(bf16x8*)&As[srow * BK + sq * 8] = av;
#pragma unroll
      for (int h = 0; h < 2; ++h) {
        const int o = col0 + h*64 + srow;
        float s1 = sc[(size_t)o*IN_F + i];
        const float4* sp = (const float4*)(sw + ((size_t)o*IN_F + i)*8);
        float4 c0 = sp[0], c1 = sp[1];
        float wv[8] = {c0.x,c0.y,c0.z,c0.w,c1.x,c1.y,c1.z,c1.w};
        bf16x8 bb;
#pragma unroll
        for (int j = 0; j < 8; ++j) bb[j] = (bf16)(wv[j]*s1);
        *(bf16x8*)&Bs[(h*64+srow)*BK + sq*8] = bb;
      }
    }
    __syncthreads();
    bf16x8 af[4], bfr[2];
#pragma unroll
    for (int mt = 0; mt < 4; ++mt)
      af[mt] = *(const bf16x8*)&As[(mt*16+r)*BK + q*8];
#pragma unroll
    for (int nt = 0; nt < 2; ++nt)
      bfr[nt] = *(const bf16x8*)&Bs[(wn+nt*16+r)*BK + q*8];
#pragma unroll
    for (int mt = 0; mt < 4; ++mt)
#pragma unroll
      for (int nt = 0; nt < 2; ++nt)
        acc[mt][nt] = __builtin_amdgcn_mfma_f32_16x16x32_bf16(af[mt], bfr[nt], acc[mt][nt], 0,0,0);
    __syncthreads();
  }
#pragma unroll
  for (int mt = 0; mt < 4; ++mt)
#pragma unroll
    for (int nt = 0; nt < 2; ++nt)
#pragma unroll
      for (int k = 0; k < 4; ++k)
        out[(size_t)(row0+mt*16+q*4+k)*N_COLS + col0+wn+nt*16+r] = acc[mt][nt][k];
}

extern "C" void kernel_launch(void* const* d_in, const int* in_sizes, int n_in,
                              void* d_out, int out_size, void* d_ws, size_t ws_size,
                              hipStream_t stream) {
  const float* x    = (const float*)d_in[0];
  const float* bw   = (const float*)d_in[1];
  const float* sw   = (const float*)d_in[2];
  const float* sc   = (const float*)d_in[3];
  float* out = (float*)d_out;

  const size_t BT_BYTES  = (size_t)N_COLS * K2 * sizeof(bf16);   // 18.9 MB
  const size_t ROW_BYTES = (size_t)K2 * sizeof(bf16);            // 18 KB
  const size_t A_BYTES   = (size_t)M_ROWS * ROW_BYTES;           // 75.5 MB
  const size_t OUT_BYTES = (size_t)M_ROWS * N_COLS * sizeof(float); // 16.8 MB

  // Split-K ladder: S=4 (full chip) -> 3 -> 2, whatever fits in ws.
  int S = 0;
  for (int c = 4; c >= 2; --c)
    if (GKT % c == 0 && BT_BYTES + A_BYTES + (size_t)c * OUT_BYTES <= ws_size) {
      S = c; break;
    }

  if (S >= 2) {
    bf16*  BT    = (bf16*)d_ws;
    bf16*  Aslab = BT + (size_t)N_COLS * K2;
    float* P     = (float*)((char*)d_ws + BT_BYTES + A_BYTES);
    prep<<<(M_ROWS * IN_F) / 256 + (N_COLS * IN_F) / 256, 256, 0, stream>>>(
        x, bw, sw, sc, Aslab, BT);
    gemm256_8p<<<S * 64, 512, 0, stream>>>(Aslab, BT, P, GKT / S);
    reduce_addN<<<(M_ROWS * N_COLS) / (4 * 256), 256, 0, stream>>>(P, out, S);
  } else {
    int SL = 0;
    for (int cand = 4096; cand >= 128; cand >>= 1)
      if (BT_BYTES + (size_t)cand * ROW_BYTES <= ws_size) { SL = cand; break; }
    if (SL) {
      bf16* BT    = (bf16*)d_ws;
      bf16* Aslab = BT + (size_t)N_COLS * K2;
      make_bt<<<(N_COLS * IN_F) / 256, 256, 0, stream>>>(bw, sw, sc, BT);
      for (int r0 = 0; r0 < M_ROWS; r0 += SL) {
        expand_a<<<(SL * IN_F) / 256, 256, 0, stream>>>(x, Aslab, r0);
        gemm_fused<<<(SL / 128) * (N_COLS / 128), 256, 0, stream>>>(
            Aslab, BT, out, out, r0, SL / 128, GKT);
      }
    } else {
      kan_fused_fallback<<<dim3(N_COLS / 128, M_ROWS / 64), 256, 0, stream>>>(
          x, bw, sw, sc, out);
    }
  }
  (void)in_sizes; (void)n_in; (void)out_size;
}